// Round 4
// baseline (259.835 us; speedup 1.0000x reference)
//
#include <hip/hip_runtime.h>
#include <hip/hip_bf16.h>
#include <stdint.h>
#include <math.h>

#define SEQ 4096
#define DIM 1024
#define NHEADS 16
#define DHEAD 64
#define INNER 1024

typedef __hip_bfloat16 bf16;
typedef __attribute__((ext_vector_type(8))) short short8;
typedef __attribute__((ext_vector_type(4))) float floatx4;

// async global->LDS, 16B per lane; lane i's 16B lands at dest + i*16.
__device__ __forceinline__ void gll16(const bf16* g, bf16* l) {
    __builtin_amdgcn_global_load_lds(
        (const __attribute__((address_space(1))) unsigned int*)g,
        (__attribute__((address_space(3))) unsigned int*)l,
        16, 0, 0);
}

__device__ __forceinline__ unsigned short f2bf_bits(float f) {
    bf16 h = __float2bfloat16(f);
    return *reinterpret_cast<unsigned short*>(&h);
}

__device__ __forceinline__ uint2 pack4bf(float a, float b, float c, float d) {
    __hip_bfloat162 lo = __float22bfloat162_rn(float2{a, b});
    __hip_bfloat162 hi = __float22bfloat162_rn(float2{c, d});
    uint2 r;
    r.x = *reinterpret_cast<unsigned*>(&lo);
    r.y = *reinterpret_cast<unsigned*>(&hi);
    return r;
}

// ---------------- prep: z=0..3 weight transpose+convert; z=4 x convert ----------------
__global__ __launch_bounds__(256) void prep_kernel(
        const float* __restrict__ x, const float* __restrict__ W0,
        const float* __restrict__ W1, const float* __restrict__ W2,
        const float* __restrict__ W3, bf16* __restrict__ xb,
        bf16* __restrict__ T0, bf16* __restrict__ T1,
        bf16* __restrict__ T2, bf16* __restrict__ T3) {
    const int tid = threadIdx.x + threadIdx.y * blockDim.x;  // 0..255
    if (blockIdx.z == 4) {
        // convert x: block (bx,by) -> chunk (by*32+bx) of 4096 floats
        int chunk = blockIdx.y * 32 + blockIdx.x;
        int base = chunk * 4096 + tid * 4;
        #pragma unroll
        for (int r = 0; r < 4; r++) {
            int i = base + r * 1024;
            float4 f = *reinterpret_cast<const float4*>(x + i);
            unsigned long long p = (unsigned long long)f2bf_bits(f.x)
                                 | ((unsigned long long)f2bf_bits(f.y) << 16)
                                 | ((unsigned long long)f2bf_bits(f.z) << 32)
                                 | ((unsigned long long)f2bf_bits(f.w) << 48);
            *reinterpret_cast<unsigned long long*>(xb + i) = p;
        }
        return;
    }
    const float* W; bf16* T;
    switch (blockIdx.z) {
        case 0:  W = W0; T = T0; break;
        case 1:  W = W1; T = T1; break;
        case 2:  W = W2; T = T2; break;
        default: W = W3; T = T3; break;
    }
    __shared__ float tile[32][33];
    int k0 = blockIdx.x * 32, n0 = blockIdx.y * 32;
    int tx = threadIdx.x, ty = threadIdx.y;
    #pragma unroll
    for (int i = 0; i < 4; i++)
        tile[ty + 8 * i][tx] = W[(size_t)(k0 + ty + 8 * i) * 1024 + n0 + tx];
    __syncthreads();
    #pragma unroll
    for (int i = 0; i < 4; i++)
        T[(size_t)(n0 + ty + 8 * i) * 1024 + k0 + tx] = __float2bfloat16(tile[tx][ty + 8 * i]);
}

// ---------------- 128x128 bf16 MFMA GEMM tile body (K=1024), m97-style ----------------
__device__ __forceinline__ void gemm128_body(const bf16* __restrict__ A,
                                             const bf16* __restrict__ Bt,
                                             int m0, int n0, floatx4 acc[4][4]) {
    __shared__ __align__(16) bf16 As[8192];
    __shared__ __align__(16) bf16 Bs[8192];
    const int tid = threadIdx.x;
    const int wave = tid >> 6;
    const int lane = tid & 63;
    const int l15 = lane & 15;
    const int quad = lane >> 4;

    #pragma unroll
    for (int i = 0; i < 4; i++)
        #pragma unroll
        for (int j = 0; j < 4; j++)
            acc[i][j] = (floatx4){0.f, 0.f, 0.f, 0.f};

    for (int k0 = 0; k0 < 1024; k0 += 64) {
        __syncthreads();
        #pragma unroll
        for (int j = 0; j < 4; j++) {
            int t = wave * 4 + j;
            int row = (t >> 1) * 16 + l15;
            int kb = (t & 1) * 32 + quad * 8;
            gll16(A + (size_t)(m0 + row) * 1024 + k0 + kb, &As[t * 512]);
            gll16(Bt + (size_t)(n0 + row) * 1024 + k0 + kb, &Bs[t * 512]);
        }
        __syncthreads();
        #pragma unroll
        for (int ks = 0; ks < 2; ks++) {
            short8 af[4], bfr[4];
            #pragma unroll
            for (int i = 0; i < 4; i++)
                af[i] = *reinterpret_cast<const short8*>(
                    &As[((((wave >> 1) * 4 + i) * 2 + ks) * 512) + lane * 8]);
            #pragma unroll
            for (int j = 0; j < 4; j++)
                bfr[j] = *reinterpret_cast<const short8*>(
                    &Bs[((((wave & 1) * 4 + j) * 2 + ks) * 512) + lane * 8]);
            #pragma unroll
            for (int i = 0; i < 4; i++)
                #pragma unroll
                for (int j = 0; j < 4; j++)
                    acc[i][j] = __builtin_amdgcn_mfma_f32_16x16x32_bf16(af[i], bfr[j], acc[i][j], 0, 0, 0);
        }
    }
}

// ---------------- QKV projection ----------------
// z=0: Q (scaled by beta*log2e so attention uses raw v_exp_f32; [h][seq][64])
// z=1: K ([h][seq][64])
// z=2: V written TRANSPOSED directly: Vt[h][d][seq] (b64 packed stores).
__global__ __launch_bounds__(256) void qkv_gemm_kernel(
        const bf16* __restrict__ xb,
        const bf16* __restrict__ Wqt, const bf16* __restrict__ Wkt, const bf16* __restrict__ Wvt,
        bf16* __restrict__ Qh, bf16* __restrict__ Kh, bf16* __restrict__ Vt) {
    const bf16* Bt;
    if (blockIdx.z == 0)      Bt = Wqt;
    else if (blockIdx.z == 1) Bt = Wkt;
    else                      Bt = Wvt;
    int n0 = blockIdx.x * 128, m0 = blockIdx.y * 128;
    floatx4 acc[4][4];
    gemm128_body(xb, Bt, m0, n0, acc);

    const int tid = threadIdx.x, wave = tid >> 6, lane = tid & 63;
    const int l15 = lane & 15, quad = lane >> 4;
    const int wm = (wave >> 1) * 64, wn = (wave & 1) * 64;
    if (blockIdx.z == 2) {
        #pragma unroll
        for (int i = 0; i < 4; i++)
            #pragma unroll
            for (int j = 0; j < 4; j++) {
                int col = n0 + wn + j * 16 + l15;
                int h = col >> 6, d = col & 63;
                int row0 = m0 + wm + i * 16 + quad * 4;
                uint2 v = pack4bf(acc[i][j][0], acc[i][j][1], acc[i][j][2], acc[i][j][3]);
                *reinterpret_cast<uint2*>(Vt + ((size_t)h * DHEAD + d) * SEQ + row0) = v;
            }
    } else {
        bf16* O = (blockIdx.z == 0) ? Qh : Kh;
        float scale = (blockIdx.z == 0) ? 0.125f * 1.4426950408889634f : 1.0f;
        #pragma unroll
        for (int i = 0; i < 4; i++)
            #pragma unroll
            for (int j = 0; j < 4; j++) {
                int col = n0 + wn + j * 16 + l15;
                int h = col >> 6, d = col & 63;
                #pragma unroll
                for (int r = 0; r < 4; r++) {
                    int row = m0 + wm + i * 16 + quad * 4 + r;
                    O[((size_t)h * SEQ + row) * DHEAD + d] = __float2bfloat16(acc[i][j][r] * scale);
                }
            }
    }
}

// ---------------- output projection: out = Oa @ Wo + bo (fp32 out) ----------------
__global__ __launch_bounds__(256) void out_gemm_kernel(
        const bf16* __restrict__ Oa, const bf16* __restrict__ Wot,
        const float* __restrict__ bo, float* __restrict__ out) {
    int n0 = blockIdx.x * 128, m0 = blockIdx.y * 128;
    floatx4 acc[4][4];
    gemm128_body(Oa, Wot, m0, n0, acc);

    const int tid = threadIdx.x, wave = tid >> 6, lane = tid & 63;
    const int l15 = lane & 15, quad = lane >> 4;
    const int wm = (wave >> 1) * 64, wn = (wave & 1) * 64;
    #pragma unroll
    for (int i = 0; i < 4; i++)
        #pragma unroll
        for (int j = 0; j < 4; j++) {
            int col = n0 + wn + j * 16 + l15;
            float b = bo[col];
            #pragma unroll
            for (int r = 0; r < 4; r++) {
                int row = m0 + wm + i * 16 + quad * 4 + r;
                out[(size_t)row * DIM + col] = acc[i][j][r] + b;
            }
        }
}

// ---------------- causal flash attention (R12: key-split waves over R11 split-key grid) ----------------
// POST-MORTEM R11: split-key WIN 90->77.5 µs; counter budget shows 83% of the
// remaining time is LDS pipe service: query-split waves each re-read the SAME
// full K and V tile (4x duplication) = 18 b128/wave/tile. (Also explains R4==R9
// neutrality — identical LDS bytes — and R10's loss: its intensity win was
// masked by a 2-block/CU occupancy cap.)
// R12: waves tile (q-pair x key-half): wave = (pr=w>>1 -> q rows pr*32..+31,
// kp=w&1 -> keys kp*32..+31 of each BK=64 tile). Each wave reads ONLY its
// K/V quarter: 4 ak + 4 av + 2 bp = 10 b128/wave/tile (was 18); Ps writes
// halve. MFMA/exp2 counts unchanged. Epilogue: cross-parity (O,l) reduction
// via 16 KB of freed K/V LDS, once per block (~1k cy, negligible).
// LDS = 40960 B exactly (one smem carve, epilogue reuses) -> 4 blocks/CU.
// Grid/piece map/combine = R11 (1536 pieces, longest-first, additive partials;
// softmax has NO max-subtraction so (O,l) partials are directly additive).
// Sᵀ = K·Qᵀ; p = v_exp_f32(s) via __builtin_amdgcn_exp2f — do NOT use exp2f
// (libcall, +15 µs R8). DO NOT: drop staging (R6), V in regs (R7 spill),
// occupancy caps < 4 blocks/CU (R10 failure mode).
__global__ __launch_bounds__(256, 4) void attention_kernel(
        const bf16* __restrict__ Qh, const bf16* __restrict__ Kh,
        const bf16* __restrict__ Vt, bf16* __restrict__ Oa,
        float* __restrict__ Op0, float* __restrict__ Op1,
        float* __restrict__ L0, float* __restrict__ L1) {
    __shared__ __align__(16) char smem[40960];
    bf16* Kshb = (bf16*)smem;                    // [2][4096] 16 KB: frag t = keygrp*2 + khalf
    bf16* Vshb = (bf16*)(smem + 16384);          // [2][4096] 16 KB: frag t = dgrp*2 + kseg
    bf16* Psb  = (bf16*)(smem + 32768);          // [4][1024] 8 KB: per-wave P frags (g*512)
    const int tid = threadIdx.x, wave = tid >> 6, lane = tid & 63;
    const int l15 = lane & 15, quad = lane >> 4;
    const int kp = wave & 1;                     // key-half parity (keys kp*32..+31)
    const int pr = wave >> 1;                    // q-pair (rows pr*32..+31)
    const int id = blockIdx.x;
    const int head = id & 15;                    // XCD id&7 serves heads {h, h+8}
    const int rk = id >> 4;                      // 0..95
    // piece map, longest-first: rk<32 -> (qt=32+rk, chunk0, len 32);
    // rk>=32: pair=(rk-32)>>1; even -> (qt=63-pair, chunk1); odd -> (qt=31-pair, single).
    int qt, ck;
    if (rk < 32) { qt = 32 + rk; ck = 0; }
    else {
        int j = rk - 32, pair = j >> 1;
        if ((j & 1) == 0) { qt = 63 - pair; ck = 1; }
        else              { qt = 31 - pair; ck = 0; }
    }
    const int ktile0 = ck ? 32 : 0;
    const int ktile1 = (qt < 32) ? (qt + 1) : (ck ? (qt + 1) : 32);
    const int qw = qt * 64 + pr * 32;            // wave's q-row base (32 rows, 2 groups)
    const size_t hoff = (size_t)head * SEQ * DHEAD;
    const bf16* Qb = Qh + hoff;
    const bf16* Kb = Kh + hoff;
    const bf16* Vb = Vt + hoff;                  // [d][seq]

    // Q as B-operand fragments: g = 16-row group, s = k-half along d
    short8 bq[2][2];
    #pragma unroll
    for (int g = 0; g < 2; g++)
        #pragma unroll
        for (int s = 0; s < 2; s++)
            bq[g][s] = *reinterpret_cast<const short8*>(
                Qb + (size_t)(qw + g * 16 + l15) * DHEAD + s * 32 + quad * 8);

    floatx4 acc_o[2][4];                         // partial Oᵀ (this key-parity): d=c*16+quad*4+r, q=g*16+l15
    #pragma unroll
    for (int g = 0; g < 2; g++)
        #pragma unroll
        for (int c = 0; c < 4; c++) acc_o[g][c] = (floatx4){0.f, 0.f, 0.f, 0.f};
    float l_part[2] = {0.f, 0.f};                // per-lane denom partials (this key-parity)

    // per-wave stage of one 64-key K tile + V tile into buffer `buf`
    auto stage = [&](int buf, int kbase) {
        #pragma unroll
        for (int j = 0; j < 2; j++) {
            int t = wave * 2 + j;                // t = 0..7 across 4 waves
            gll16(Kb + (size_t)(kbase + (t >> 1) * 16 + l15) * DHEAD + (t & 1) * 32 + quad * 8,
                  &Kshb[buf * 4096 + t * 512]);
            gll16(Vb + (size_t)((t >> 1) * 16 + l15) * SEQ + kbase + (t & 1) * 32 + quad * 8,
                  &Vshb[buf * 4096 + t * 512]);
        }
    };

    stage(0, ktile0 * 64);
    __syncthreads();                             // vmcnt(0) drain + first tile visible
    int cur = 0;
    for (int kt = ktile0; kt < ktile1; kt++) {
        const int kbase = kt * 64;
        if (kt + 1 < ktile1) stage(cur ^ 1, (kt + 1) * 64);  // async prefetch

        // Sᵀ = K·Qᵀ on this wave's key quarter: 4 ak reads feed 8 MFMAs
        floatx4 st[2][2];                        // [qgrp g][keygrp kg within half]
        #pragma unroll
        for (int g = 0; g < 2; g++)
            #pragma unroll
            for (int kg = 0; kg < 2; kg++) st[g][kg] = (floatx4){0.f, 0.f, 0.f, 0.f};
        __builtin_amdgcn_s_setprio(1);
        #pragma unroll
        for (int kg = 0; kg < 2; kg++) {
            short8 ak0 = *reinterpret_cast<const short8*>(
                &Kshb[cur * 4096 + ((kp * 2 + kg) * 2 + 0) * 512 + lane * 8]);
            short8 ak1 = *reinterpret_cast<const short8*>(
                &Kshb[cur * 4096 + ((kp * 2 + kg) * 2 + 1) * 512 + lane * 8]);
            st[0][kg] = __builtin_amdgcn_mfma_f32_16x16x32_bf16(ak0, bq[0][0], st[0][kg], 0, 0, 0);
            st[0][kg] = __builtin_amdgcn_mfma_f32_16x16x32_bf16(ak1, bq[0][1], st[0][kg], 0, 0, 0);
            st[1][kg] = __builtin_amdgcn_mfma_f32_16x16x32_bf16(ak0, bq[1][0], st[1][kg], 0, 0, 0);
            st[1][kg] = __builtin_amdgcn_mfma_f32_16x16x32_bf16(ak1, bq[1][1], st[1][kg], 0, 0, 0);
        }
        __builtin_amdgcn_s_setprio(0);
        // causal mask: key = kbase + kp*32 + kg*16 + quad*4 + r, q = qw + g*16 + l15
        #pragma unroll
        for (int g = 0; g < 2; g++) {
            if (kbase + kp * 32 + 31 > qw + g * 16) {   // wave-uniform guard
                int base0 = kbase + kp * 32 + quad * 4 - (qw + g * 16) - l15;
                #pragma unroll
                for (int kg = 0; kg < 2; kg++) {
                    int base = base0 + kg * 16;
                    #pragma unroll
                    for (int r = 0; r < 4; r++)
                        if (base + r > 0) st[g][kg][r] = -1e30f;
                }
            }
        }
        // p = 2^s (masked -> 0); per-lane denom; pack into per-wave P frags
        #pragma unroll
        for (int g = 0; g < 2; g++)
            #pragma unroll
            for (int kg = 0; kg < 2; kg++) {
                float p0 = __builtin_amdgcn_exp2f(st[g][kg][0]);
                float p1 = __builtin_amdgcn_exp2f(st[g][kg][1]);
                float p2 = __builtin_amdgcn_exp2f(st[g][kg][2]);
                float p3 = __builtin_amdgcn_exp2f(st[g][kg][3]);
                l_part[g] += (p0 + p1) + (p2 + p3);
                int elem = g * 512 + (l15 + 16 * (kg * 2 + (quad >> 1))) * 8 + (quad & 1) * 4;
                *reinterpret_cast<uint2*>(&Psb[wave * 1024 + elem]) = pack4bf(p0, p1, p2, p3);
            }
        // partial Oᵀ += Vᵀ[:, own keys] · Pᵀ: 4 av + 2 bp reads feed 8 MFMAs
        __builtin_amdgcn_s_setprio(1);
        {
            short8 bp0 = *reinterpret_cast<const short8*>(&Psb[wave * 1024 + 0 * 512 + lane * 8]);
            short8 bp1 = *reinterpret_cast<const short8*>(&Psb[wave * 1024 + 1 * 512 + lane * 8]);
            #pragma unroll
            for (int c = 0; c < 4; c++) {
                short8 av = *reinterpret_cast<const short8*>(
                    &Vshb[cur * 4096 + (c * 2 + kp) * 512 + lane * 8]);
                acc_o[0][c] = __builtin_amdgcn_mfma_f32_16x16x32_bf16(av, bp0, acc_o[0][c], 0, 0, 0);
                acc_o[1][c] = __builtin_amdgcn_mfma_f32_16x16x32_bf16(av, bp1, acc_o[1][c], 0, 0, 0);
            }
        }
        __builtin_amdgcn_s_setprio(0);

        __syncthreads();                         // readers done + prefetch drained
        cur ^= 1;
    }
    // per-wave denom: sum the 4 quad-lanes (covers this wave's key-parity only)
    float lv[2];
    #pragma unroll
    for (int g = 0; g < 2; g++) {
        float l = l_part[g];
        l += __shfl_xor(l, 16, 64);
        l += __shfl_xor(l, 32, 64);
        lv[g] = l;
    }
    // cross-parity reduction via freed LDS: donors = kp==1, receivers = kp==0
    __syncthreads();                             // all tile-LDS use complete
    floatx4* Red = (floatx4*)smem;               // 2 pairs x 8 frags x 64 lanes x 16B = 16 KB
    float* Lred = (float*)(smem + 32768);        // 2 pairs x 32 q x 4B = 256 B
    if (kp == 1) {
        #pragma unroll
        for (int g = 0; g < 2; g++)
            #pragma unroll
            for (int c = 0; c < 4; c++)
                Red[pr * 512 + (g * 4 + c) * 64 + lane] = acc_o[g][c];
        if (quad == 0) {
            Lred[pr * 32 + l15] = lv[0];
            Lred[pr * 32 + 16 + l15] = lv[1];
        }
    }
    __syncthreads();
    if (kp == 0) {
        #pragma unroll
        for (int g = 0; g < 2; g++)
            #pragma unroll
            for (int c = 0; c < 4; c++) {
                floatx4 o = Red[pr * 512 + (g * 4 + c) * 64 + lane];
                acc_o[g][c][0] += o[0]; acc_o[g][c][1] += o[1];
                acc_o[g][c][2] += o[2]; acc_o[g][c][3] += o[3];
            }
        lv[0] += Lred[pr * 32 + l15];
        lv[1] += Lred[pr * 32 + 16 + l15];
        #pragma unroll
        for (int g = 0; g < 2; g++) {
            const int q = qw + g * 16 + l15;
            if (qt < 32) {
                // single-chunk: finalize here. O row-major [SEQ][INNER].
                float rcp = 1.0f / lv[g];
                #pragma unroll
                for (int c = 0; c < 4; c++) {
                    uint2 v = pack4bf(acc_o[g][c][0] * rcp, acc_o[g][c][1] * rcp,
                                      acc_o[g][c][2] * rcp, acc_o[g][c][3] * rcp);
                    *reinterpret_cast<uint2*>(
                        Oa + (size_t)q * INNER + head * DHEAD + c * 16 + quad * 4) = v;
                }
            } else {
                // split: write unnormalized fp32 partials (q in [2048,4096))
                float* Op = ck ? Op1 : Op0;
                float* Lp = ck ? L1 : L0;
                if (quad == 0) Lp[head * 2048 + (q - 2048)] = lv[g];
                #pragma unroll
                for (int c = 0; c < 4; c++)
                    *reinterpret_cast<floatx4*>(
                        Op + (size_t)(q - 2048) * INNER + head * DHEAD + c * 16 + quad * 4) = acc_o[g][c];
            }
        }
    }
}

// ---------------- combine: rows 2048..4095 = (O0+O1)/(l0+l1) -> bf16 Oa ----------------
__global__ __launch_bounds__(256) void combine_kernel(
        const float* __restrict__ Op0, const float* __restrict__ Op1,
        const float* __restrict__ L0, const float* __restrict__ L1,
        bf16* __restrict__ Oa) {
    int idx = blockIdx.x * 256 + threadIdx.x;    // 524288 threads, 4 floats each
    int row = idx >> 8;                          // 0..2047 (q = 2048 + row)
    int c4 = (idx & 255) * 4;                    // col base
    int head = c4 >> 6;
    float l = L0[head * 2048 + row] + L1[head * 2048 + row];
    float rcp = 1.0f / l;
    float4 a = *reinterpret_cast<const float4*>(Op0 + (size_t)row * INNER + c4);
    float4 b = *reinterpret_cast<const float4*>(Op1 + (size_t)row * INNER + c4);
    uint2 v = pack4bf((a.x + b.x) * rcp, (a.y + b.y) * rcp,
                      (a.z + b.z) * rcp, (a.w + b.w) * rcp);
    *reinterpret_cast<uint2*>(Oa + (size_t)(2048 + row) * INNER + c4) = v;
}

extern "C" void kernel_launch(void* const* d_in, const int* in_sizes, int n_in,
                              void* d_out, int out_size, void* d_ws, size_t ws_size,
                              hipStream_t stream) {
    const float* x  = (const float*)d_in[0];
    const float* Wq = (const float*)d_in[1];
    const float* Wk = (const float*)d_in[2];
    const float* Wv = (const float*)d_in[3];
    const float* Wo = (const float*)d_in[4];
    const float* bo = (const float*)d_in[5];
    float* out = (float*)d_out;

    char* ws = (char*)d_ws;
    size_t off = 0;
    bf16* xb  = (bf16*)(ws + off); off += (size_t)SEQ * DIM * 2;
    bf16* Wqt = (bf16*)(ws + off); off += (size_t)DIM * INNER * 2;
    bf16* Wkt = (bf16*)(ws + off); off += (size_t)DIM * INNER * 2;
    bf16* Wvt = (bf16*)(ws + off); off += (size_t)DIM * INNER * 2;
    bf16* Wot = (bf16*)(ws + off); off += (size_t)INNER * DIM * 2;
    bf16* Qh  = (bf16*)(ws + off); off += (size_t)NHEADS * SEQ * DHEAD * 2;
    bf16* Kh  = (bf16*)(ws + off); off += (size_t)NHEADS * SEQ * DHEAD * 2;
    bf16* Vtr = (bf16*)(ws + off); off += (size_t)NHEADS * DHEAD * SEQ * 2;
    bf16* Oa  = (bf16*)(ws + off); off += (size_t)SEQ * INNER * 2;
    float* Op0 = (float*)(ws + off); off += (size_t)(SEQ / 2) * INNER * 4;  // 8 MB
    float* Op1 = (float*)(ws + off); off += (size_t)(SEQ / 2) * INNER * 4;  // 8 MB
    float* L0  = (float*)(ws + off); off += (size_t)NHEADS * (SEQ / 2) * 4;
    float* L1  = (float*)(ws + off); off += (size_t)NHEADS * (SEQ / 2) * 4;  // ~64.5 MB total

    prep_kernel<<<dim3(32, 32, 5), dim3(32, 8), 0, stream>>>(x, Wq, Wk, Wv, Wo,
                                                             xb, Wqt, Wkt, Wvt, Wot);
    qkv_gemm_kernel<<<dim3(8, 32, 3), 256, 0, stream>>>(xb, Wqt, Wkt, Wvt, Qh, Kh, Vtr);
    attention_kernel<<<1536, 256, 0, stream>>>(Qh, Kh, Vtr, Oa, Op0, Op1, L0, L1);
    combine_kernel<<<2048, 256, 0, stream>>>(Op0, Op1, L0, L1, Oa);
    out_gemm_kernel<<<dim3(8, 32), 256, 0, stream>>>(Oa, Wot, bo, out);
}

// Round 5
// 248.462 us; speedup vs baseline: 1.0458x; 1.0458x over previous
//
#include <hip/hip_runtime.h>
#include <hip/hip_bf16.h>
#include <stdint.h>
#include <math.h>

#define SEQ 4096
#define DIM 1024
#define NHEADS 16
#define DHEAD 64
#define INNER 1024

typedef __hip_bfloat16 bf16;
typedef __attribute__((ext_vector_type(8))) short short8;
typedef __attribute__((ext_vector_type(4))) float floatx4;
typedef __attribute__((ext_vector_type(16))) float floatx16;

// async global->LDS, 16B per lane; lane i's 16B lands at dest + i*16.
__device__ __forceinline__ void gll16(const bf16* g, bf16* l) {
    __builtin_amdgcn_global_load_lds(
        (const __attribute__((address_space(1))) unsigned int*)g,
        (__attribute__((address_space(3))) unsigned int*)l,
        16, 0, 0);
}

__device__ __forceinline__ unsigned short f2bf_bits(float f) {
    bf16 h = __float2bfloat16(f);
    return *reinterpret_cast<unsigned short*>(&h);
}

__device__ __forceinline__ uint2 pack4bf(float a, float b, float c, float d) {
    __hip_bfloat162 lo = __float22bfloat162_rn(float2{a, b});
    __hip_bfloat162 hi = __float22bfloat162_rn(float2{c, d});
    uint2 r;
    r.x = *reinterpret_cast<unsigned*>(&lo);
    r.y = *reinterpret_cast<unsigned*>(&hi);
    return r;
}

// pack two f32 -> one dword of 2 bf16 (lo in [15:0], hi in [31:16]), RNE
__device__ __forceinline__ unsigned pkbf(float lo, float hi) {
    __hip_bfloat162 h = __float22bfloat162_rn(float2{lo, hi});
    return *reinterpret_cast<unsigned*>(&h);
}

// ---------------- prep: z=0..3 weight transpose+convert; z=4 x convert ----------------
__global__ __launch_bounds__(256) void prep_kernel(
        const float* __restrict__ x, const float* __restrict__ W0,
        const float* __restrict__ W1, const float* __restrict__ W2,
        const float* __restrict__ W3, bf16* __restrict__ xb,
        bf16* __restrict__ T0, bf16* __restrict__ T1,
        bf16* __restrict__ T2, bf16* __restrict__ T3) {
    const int tid = threadIdx.x + threadIdx.y * blockDim.x;  // 0..255
    if (blockIdx.z == 4) {
        // convert x: block (bx,by) -> chunk (by*32+bx) of 4096 floats
        int chunk = blockIdx.y * 32 + blockIdx.x;
        int base = chunk * 4096 + tid * 4;
        #pragma unroll
        for (int r = 0; r < 4; r++) {
            int i = base + r * 1024;
            float4 f = *reinterpret_cast<const float4*>(x + i);
            unsigned long long p = (unsigned long long)f2bf_bits(f.x)
                                 | ((unsigned long long)f2bf_bits(f.y) << 16)
                                 | ((unsigned long long)f2bf_bits(f.z) << 32)
                                 | ((unsigned long long)f2bf_bits(f.w) << 48);
            *reinterpret_cast<unsigned long long*>(xb + i) = p;
        }
        return;
    }
    const float* W; bf16* T;
    switch (blockIdx.z) {
        case 0:  W = W0; T = T0; break;
        case 1:  W = W1; T = T1; break;
        case 2:  W = W2; T = T2; break;
        default: W = W3; T = T3; break;
    }
    __shared__ float tile[32][33];
    int k0 = blockIdx.x * 32, n0 = blockIdx.y * 32;
    int tx = threadIdx.x, ty = threadIdx.y;
    #pragma unroll
    for (int i = 0; i < 4; i++)
        tile[ty + 8 * i][tx] = W[(size_t)(k0 + ty + 8 * i) * 1024 + n0 + tx];
    __syncthreads();
    #pragma unroll
    for (int i = 0; i < 4; i++)
        T[(size_t)(n0 + ty + 8 * i) * 1024 + k0 + tx] = __float2bfloat16(tile[tx][ty + 8 * i]);
}

// ---------------- 128x128 bf16 MFMA GEMM tile body (K=1024), m97-style ----------------
__device__ __forceinline__ void gemm128_body(const bf16* __restrict__ A,
                                             const bf16* __restrict__ Bt,
                                             int m0, int n0, floatx4 acc[4][4]) {
    __shared__ __align__(16) bf16 As[8192];
    __shared__ __align__(16) bf16 Bs[8192];
    const int tid = threadIdx.x;
    const int wave = tid >> 6;
    const int lane = tid & 63;
    const int l15 = lane & 15;
    const int quad = lane >> 4;

    #pragma unroll
    for (int i = 0; i < 4; i++)
        #pragma unroll
        for (int j = 0; j < 4; j++)
            acc[i][j] = (floatx4){0.f, 0.f, 0.f, 0.f};

    for (int k0 = 0; k0 < 1024; k0 += 64) {
        __syncthreads();
        #pragma unroll
        for (int j = 0; j < 4; j++) {
            int t = wave * 4 + j;
            int row = (t >> 1) * 16 + l15;
            int kb = (t & 1) * 32 + quad * 8;
            gll16(A + (size_t)(m0 + row) * 1024 + k0 + kb, &As[t * 512]);
            gll16(Bt + (size_t)(n0 + row) * 1024 + k0 + kb, &Bs[t * 512]);
        }
        __syncthreads();
        #pragma unroll
        for (int ks = 0; ks < 2; ks++) {
            short8 af[4], bfr[4];
            #pragma unroll
            for (int i = 0; i < 4; i++)
                af[i] = *reinterpret_cast<const short8*>(
                    &As[((((wave >> 1) * 4 + i) * 2 + ks) * 512) + lane * 8]);
            #pragma unroll
            for (int j = 0; j < 4; j++)
                bfr[j] = *reinterpret_cast<const short8*>(
                    &Bs[((((wave & 1) * 4 + j) * 2 + ks) * 512) + lane * 8]);
            #pragma unroll
            for (int i = 0; i < 4; i++)
                #pragma unroll
                for (int j = 0; j < 4; j++)
                    acc[i][j] = __builtin_amdgcn_mfma_f32_16x16x32_bf16(af[i], bfr[j], acc[i][j], 0, 0, 0);
        }
    }
}

// ---------------- QKV projection ----------------
// z=0: Q (scaled by beta*log2e so attention uses raw v_exp_f32; [h][seq][64])
// z=1: K ([h][seq][64])
// z=2: V written TRANSPOSED directly: Vt[h][d][seq] (b64 packed stores).
__global__ __launch_bounds__(256) void qkv_gemm_kernel(
        const bf16* __restrict__ xb,
        const bf16* __restrict__ Wqt, const bf16* __restrict__ Wkt, const bf16* __restrict__ Wvt,
        bf16* __restrict__ Qh, bf16* __restrict__ Kh, bf16* __restrict__ Vt) {
    const bf16* Bt;
    if (blockIdx.z == 0)      Bt = Wqt;
    else if (blockIdx.z == 1) Bt = Wkt;
    else                      Bt = Wvt;
    int n0 = blockIdx.x * 128, m0 = blockIdx.y * 128;
    floatx4 acc[4][4];
    gemm128_body(xb, Bt, m0, n0, acc);

    const int tid = threadIdx.x, wave = tid >> 6, lane = tid & 63;
    const int l15 = lane & 15, quad = lane >> 4;
    const int wm = (wave >> 1) * 64, wn = (wave & 1) * 64;
    if (blockIdx.z == 2) {
        #pragma unroll
        for (int i = 0; i < 4; i++)
            #pragma unroll
            for (int j = 0; j < 4; j++) {
                int col = n0 + wn + j * 16 + l15;
                int h = col >> 6, d = col & 63;
                int row0 = m0 + wm + i * 16 + quad * 4;
                uint2 v = pack4bf(acc[i][j][0], acc[i][j][1], acc[i][j][2], acc[i][j][3]);
                *reinterpret_cast<uint2*>(Vt + ((size_t)h * DHEAD + d) * SEQ + row0) = v;
            }
    } else {
        bf16* O = (blockIdx.z == 0) ? Qh : Kh;
        float scale = (blockIdx.z == 0) ? 0.125f * 1.4426950408889634f : 1.0f;
        #pragma unroll
        for (int i = 0; i < 4; i++)
            #pragma unroll
            for (int j = 0; j < 4; j++) {
                int col = n0 + wn + j * 16 + l15;
                int h = col >> 6, d = col & 63;
                #pragma unroll
                for (int r = 0; r < 4; r++) {
                    int row = m0 + wm + i * 16 + quad * 4 + r;
                    O[((size_t)h * SEQ + row) * DHEAD + d] = __float2bfloat16(acc[i][j][r] * scale);
                }
            }
    }
}

// ---------------- output projection: out = Oa @ Wo + bo (fp32 out) ----------------
__global__ __launch_bounds__(256) void out_gemm_kernel(
        const bf16* __restrict__ Oa, const bf16* __restrict__ Wot,
        const float* __restrict__ bo, float* __restrict__ out) {
    int n0 = blockIdx.x * 128, m0 = blockIdx.y * 128;
    floatx4 acc[4][4];
    gemm128_body(Oa, Wot, m0, n0, acc);

    const int tid = threadIdx.x, wave = tid >> 6, lane = tid & 63;
    const int l15 = lane & 15, quad = lane >> 4;
    const int wm = (wave >> 1) * 64, wn = (wave & 1) * 64;
    #pragma unroll
    for (int i = 0; i < 4; i++)
        #pragma unroll
        for (int j = 0; j < 4; j++) {
            int col = n0 + wn + j * 16 + l15;
            float b = bo[col];
            #pragma unroll
            for (int r = 0; r < 4; r++) {
                int row = m0 + wm + i * 16 + quad * 4 + r;
                out[(size_t)row * DIM + col] = acc[i][j][r] + b;
            }
        }
}

// ---------------- causal flash attention (R13: 32x32 MFMA + in-register P) ----------------
// POST-MORTEM R12: cutting LDS reads 44% at same occupancy made it SLOWER
// (77.5->88.5) -> NOT LDS-BW-bound. All pipes <35% busy => instruction-issue /
// serial-overhead bound: R11 issued ~130 instrs per 16 small MFMAs (262 kFLOP).
// R13 cuts instructions/FLOP ~3.6x, following the m214 reference structure:
//   * mfma_f32_32x32x16_bf16 (2x FLOP/instr, 2x FLOP/LDS-byte). 4 waves x 32 q
//     = 128-row blocks; block-tiles halve to 16896.
//   * S^T = K.Q^T: C/D layout key=(reg&3)+8*(reg>>2)+4*(lane>>5), q=lane&31
//     (m74/m101-verified; matches m214's crow()).
//   * P built IN-REGISTER for PV (T12): per 16-key slot, 4 cvt_pk +
//     2 v_permlane32_swap_b32 produce the B-frag (k=8*half+j) directly from
//     S^T regs. swap(A_w,B_w) -> (word w, word w+2). NO Ps LDS round-trip.
//   * LDS 32 KB (K/V dbuf only) -> 4 blocks/CU; VGPR-capped by (256,4).
//   * split-key grid (768 pieces, longest-first, additive partials since
//     softmax has NO max-subtraction) + combine kernel = R11 (proven).
// p = v_exp_f32(s) via __builtin_amdgcn_exp2f — do NOT use exp2f (libcall,
// +15 µs R8). DO NOT: drop staging (R6), occupancy <4 blk/CU (R10),
// per-wave K/V-quarter split (R12, slower).
#define PV_STEP(P, KTG)                                                              \
    do {                                                                             \
        const int rb_ = ((KTG) & 1) * 8;                                             \
        unsigned A0_ = pkbf((P)[rb_ + 0], (P)[rb_ + 1]);                             \
        unsigned B0_ = pkbf((P)[rb_ + 4], (P)[rb_ + 5]);                             \
        unsigned A1_ = pkbf((P)[rb_ + 2], (P)[rb_ + 3]);                             \
        unsigned B1_ = pkbf((P)[rb_ + 6], (P)[rb_ + 7]);                             \
        asm("v_permlane32_swap_b32 %0, %1" : "+v"(A0_), "+v"(B0_));                  \
        asm("v_permlane32_swap_b32 %0, %1" : "+v"(A1_), "+v"(B1_));                  \
        uint4 w_; w_.x = A0_; w_.y = A1_; w_.z = B0_; w_.w = B1_;                    \
        short8 bp_ = *reinterpret_cast<short8*>(&w_);                                \
        short8 av0_ = *reinterpret_cast<const short8*>(                              \
            &Vsh[cur][(KTG) * 512 + lane * 8]);                                      \
        short8 av1_ = *reinterpret_cast<const short8*>(                              \
            &Vsh[cur][(4 + (KTG)) * 512 + lane * 8]);                                \
        acc0 = __builtin_amdgcn_mfma_f32_32x32x16_bf16(av0_, bp_, acc0, 0, 0, 0);    \
        acc1 = __builtin_amdgcn_mfma_f32_32x32x16_bf16(av1_, bp_, acc1, 0, 0, 0);    \
    } while (0)

__global__ __launch_bounds__(256, 4) void attention_kernel(
        const bf16* __restrict__ Qh, const bf16* __restrict__ Kh,
        const bf16* __restrict__ Vt, bf16* __restrict__ Oa,
        float* __restrict__ Op0, float* __restrict__ Op1,
        float* __restrict__ L0, float* __restrict__ L1) {
    __shared__ __align__(16) bf16 Ksh[2][4096];  // 8 KB/buf: chunk t=g*4+kc (keys g*32.., k kc*16..)
    __shared__ __align__(16) bf16 Vsh[2][4096];  // 8 KB/buf: chunk t=dg*4+kt (d dg*32.., key kt*16..)
    const int tid = threadIdx.x, wave = tid >> 6, lane = tid & 63;
    const int ql = lane & 31, half = lane >> 5;
    const int h8 = half * 8;
    const int id = blockIdx.x;
    const int head = id & 15;                    // XCD id&7 serves heads {h, h+8}
    const int rk = id >> 4;                      // 0..47
    // piece map, longest-first over 128-row q-tiles t:
    // rk<16: (t=16+rk, ck=0, len 32); rk 16..31: (t=47-rk, ck=1, len 2(t-15));
    // rk 32..47: (t=47-rk, single, len 2t+2).
    int t, ck;
    if (rk < 16)      { t = 16 + rk; ck = 0; }
    else if (rk < 32) { t = 47 - rk; ck = 1; }
    else              { t = 47 - rk; ck = 0; }
    const bool split = (t >= 16);
    const int ktile0 = (split && ck == 1) ? 32 : 0;
    const int ktile1 = (split && ck == 0) ? 32 : (2 * t + 2);
    const int qw = t * 128 + wave * 32;          // wave's 32 q-rows
    const int q = qw + ql;                       // this lane's q-row (n = lane&31)
    const size_t hoff = (size_t)head * SEQ * DHEAD;
    const bf16* Qb = Qh + hoff;
    const bf16* Kb = Kh + hoff;
    const bf16* Vb = Vt + hoff;                  // [d][seq]

    // Q as B-frags for 32x32x16: lane n=q, k = kc*16 + 8*half + j
    short8 bq[4];
    #pragma unroll
    for (int kc = 0; kc < 4; kc++)
        bq[kc] = *reinterpret_cast<const short8*>(
            Qb + (size_t)q * DHEAD + kc * 16 + h8);

    floatx16 acc0, acc1;                         // O: d = (reg&3)+8*(reg>>2)+4*half (+32 for acc1), col q
    #pragma unroll
    for (int r = 0; r < 16; r++) { acc0[r] = 0.f; acc1[r] = 0.f; }
    float l_part = 0.f;

    // per-wave stage of one 64-key K tile + V tile into buffer `buf`
    auto stage = [&](int buf, int kbase) {
        #pragma unroll
        for (int j = 0; j < 2; j++) {
            int tc = wave * 2 + j;               // 0..7 across 4 waves
            gll16(Kb + (size_t)(kbase + (tc >> 2) * 32 + ql) * DHEAD + (tc & 3) * 16 + h8,
                  &Ksh[buf][tc * 512]);
            gll16(Vb + (size_t)((tc >> 2) * 32 + ql) * SEQ + kbase + (tc & 3) * 16 + h8,
                  &Vsh[buf][tc * 512]);
        }
    };

    stage(0, ktile0 * 64);
    __syncthreads();                             // vmcnt(0) drain + first tile visible
    int cur = 0;
    for (int kt = ktile0; kt < ktile1; kt++) {
        const int kbase = kt * 64;
        if (kt + 1 < ktile1) stage(cur ^ 1, (kt + 1) * 64);  // async prefetch

        // S^T = K·Q^T: 8 A-frag reads feed 8 32x32x16 MFMAs (2 key-groups)
        floatx16 s0, s1;
        #pragma unroll
        for (int r = 0; r < 16; r++) { s0[r] = 0.f; s1[r] = 0.f; }
        __builtin_amdgcn_s_setprio(1);
        #pragma unroll
        for (int kc = 0; kc < 4; kc++) {
            short8 ak0 = *reinterpret_cast<const short8*>(&Ksh[cur][kc * 512 + lane * 8]);
            short8 ak1 = *reinterpret_cast<const short8*>(&Ksh[cur][(4 + kc) * 512 + lane * 8]);
            s0 = __builtin_amdgcn_mfma_f32_32x32x16_bf16(ak0, bq[kc], s0, 0, 0, 0);
            s1 = __builtin_amdgcn_mfma_f32_32x32x16_bf16(ak1, bq[kc], s1, 0, 0, 0);
        }
        __builtin_amdgcn_s_setprio(0);
        // causal mask: key = kbase + 32*sg + (r&3)+8*(r>>2)+4*half, q = q
        if (kbase + 63 > qw) {                   // wave-uniform
            int base0 = kbase + half * 4 - q;
            #pragma unroll
            for (int r = 0; r < 16; r++) {
                int off = (r & 3) + 8 * (r >> 2);
                if (base0 + off > 0)      s0[r] = -1e30f;
                if (base0 + 32 + off > 0) s1[r] = -1e30f;
            }
        }
        // p = 2^s in place (masked -> 0); per-lane denom partial
        #pragma unroll
        for (int r = 0; r < 16; r++) {
            s0[r] = __builtin_amdgcn_exp2f(s0[r]);
            s1[r] = __builtin_amdgcn_exp2f(s1[r]);
            l_part += s0[r] + s1[r];
        }
        // O += V^T·P: per 16-key slot build bp in-register (T12) + 2 MFMAs
        __builtin_amdgcn_s_setprio(1);
        PV_STEP(s0, 0); PV_STEP(s0, 1); PV_STEP(s1, 2); PV_STEP(s1, 3);
        __builtin_amdgcn_s_setprio(0);

        __syncthreads();                         // readers done + prefetch drained
        cur ^= 1;
    }
    // denom: lane holds half the keys; other half sits at lane^32
    float l = l_part + __shfl_xor(l_part, 32, 64);
    if (!split) {
        // single-chunk: finalize. Oa row-major [SEQ][INNER].
        float rcp = 1.0f / l;
        #pragma unroll
        for (int a = 0; a < 4; a++) {
            int d0 = 8 * a + half * 4;
            uint2 v0 = pack4bf(acc0[4 * a + 0] * rcp, acc0[4 * a + 1] * rcp,
                               acc0[4 * a + 2] * rcp, acc0[4 * a + 3] * rcp);
            *reinterpret_cast<uint2*>(Oa + (size_t)q * INNER + head * DHEAD + d0) = v0;
            uint2 v1 = pack4bf(acc1[4 * a + 0] * rcp, acc1[4 * a + 1] * rcp,
                               acc1[4 * a + 2] * rcp, acc1[4 * a + 3] * rcp);
            *reinterpret_cast<uint2*>(Oa + (size_t)q * INNER + head * DHEAD + 32 + d0) = v1;
        }
    } else {
        // split: write unnormalized fp32 partials (q in [2048,4096))
        float* Op = ck ? Op1 : Op0;
        float* Lp = ck ? L1 : L0;
        if (half == 0) Lp[head * 2048 + (q - 2048)] = l;
        #pragma unroll
        for (int a = 0; a < 4; a++) {
            int d0 = 8 * a + half * 4;
            floatx4 v0 = {acc0[4 * a + 0], acc0[4 * a + 1], acc0[4 * a + 2], acc0[4 * a + 3]};
            *reinterpret_cast<floatx4*>(
                Op + (size_t)(q - 2048) * INNER + head * DHEAD + d0) = v0;
            floatx4 v1 = {acc1[4 * a + 0], acc1[4 * a + 1], acc1[4 * a + 2], acc1[4 * a + 3]};
            *reinterpret_cast<floatx4*>(
                Op + (size_t)(q - 2048) * INNER + head * DHEAD + 32 + d0) = v1;
        }
    }
}

// ---------------- combine: rows 2048..4095 = (O0+O1)/(l0+l1) -> bf16 Oa ----------------
__global__ __launch_bounds__(256) void combine_kernel(
        const float* __restrict__ Op0, const float* __restrict__ Op1,
        const float* __restrict__ L0, const float* __restrict__ L1,
        bf16* __restrict__ Oa) {
    int idx = blockIdx.x * 256 + threadIdx.x;    // 524288 threads, 4 floats each
    int row = idx >> 8;                          // 0..2047 (q = 2048 + row)
    int c4 = (idx & 255) * 4;                    // col base
    int head = c4 >> 6;
    float l = L0[head * 2048 + row] + L1[head * 2048 + row];
    float rcp = 1.0f / l;
    float4 a = *reinterpret_cast<const float4*>(Op0 + (size_t)row * INNER + c4);
    float4 b = *reinterpret_cast<const float4*>(Op1 + (size_t)row * INNER + c4);
    uint2 v = pack4bf((a.x + b.x) * rcp, (a.y + b.y) * rcp,
                      (a.z + b.z) * rcp, (a.w + b.w) * rcp);
    *reinterpret_cast<uint2*>(Oa + (size_t)(2048 + row) * INNER + c4) = v;
}

extern "C" void kernel_launch(void* const* d_in, const int* in_sizes, int n_in,
                              void* d_out, int out_size, void* d_ws, size_t ws_size,
                              hipStream_t stream) {
    const float* x  = (const float*)d_in[0];
    const float* Wq = (const float*)d_in[1];
    const float* Wk = (const float*)d_in[2];
    const float* Wv = (const float*)d_in[3];
    const float* Wo = (const float*)d_in[4];
    const float* bo = (const float*)d_in[5];
    float* out = (float*)d_out;

    char* ws = (char*)d_ws;
    size_t off = 0;
    bf16* xb  = (bf16*)(ws + off); off += (size_t)SEQ * DIM * 2;
    bf16* Wqt = (bf16*)(ws + off); off += (size_t)DIM * INNER * 2;
    bf16* Wkt = (bf16*)(ws + off); off += (size_t)DIM * INNER * 2;
    bf16* Wvt = (bf16*)(ws + off); off += (size_t)DIM * INNER * 2;
    bf16* Wot = (bf16*)(ws + off); off += (size_t)INNER * DIM * 2;
    bf16* Qh  = (bf16*)(ws + off); off += (size_t)NHEADS * SEQ * DHEAD * 2;
    bf16* Kh  = (bf16*)(ws + off); off += (size_t)NHEADS * SEQ * DHEAD * 2;
    bf16* Vtr = (bf16*)(ws + off); off += (size_t)NHEADS * DHEAD * SEQ * 2;
    bf16* Oa  = (bf16*)(ws + off); off += (size_t)SEQ * INNER * 2;
    float* Op0 = (float*)(ws + off); off += (size_t)(SEQ / 2) * INNER * 4;  // 8 MB
    float* Op1 = (float*)(ws + off); off += (size_t)(SEQ / 2) * INNER * 4;  // 8 MB
    float* L0  = (float*)(ws + off); off += (size_t)NHEADS * (SEQ / 2) * 4;
    float* L1  = (float*)(ws + off); off += (size_t)NHEADS * (SEQ / 2) * 4;  // ~64.5 MB total

    prep_kernel<<<dim3(32, 32, 5), dim3(32, 8), 0, stream>>>(x, Wq, Wk, Wv, Wo,
                                                             xb, Wqt, Wkt, Wvt, Wot);
    qkv_gemm_kernel<<<dim3(8, 32, 3), 256, 0, stream>>>(xb, Wqt, Wkt, Wvt, Qh, Kh, Vtr);
    attention_kernel<<<768, 256, 0, stream>>>(Qh, Kh, Vtr, Oa, Op0, Op1, L0, L1);
    combine_kernel<<<2048, 256, 0, stream>>>(Op0, Op1, L0, L1, Oa);
    out_gemm_kernel<<<dim3(8, 32), 256, 0, stream>>>(Oa, Wot, bo, out);
}

// Round 6
// 237.381 us; speedup vs baseline: 1.0946x; 1.0467x over previous
//
#include <hip/hip_runtime.h>
#include <hip/hip_bf16.h>
#include <stdint.h>
#include <math.h>

#define SEQ 4096
#define DIM 1024
#define NHEADS 16
#define DHEAD 64
#define INNER 1024

typedef __hip_bfloat16 bf16;
typedef __attribute__((ext_vector_type(8))) short short8;
typedef __attribute__((ext_vector_type(4))) float floatx4;
typedef __attribute__((ext_vector_type(16))) float floatx16;

// async global->LDS, 16B per lane; lane i's 16B lands at dest + i*16.
__device__ __forceinline__ void gll16(const bf16* g, bf16* l) {
    __builtin_amdgcn_global_load_lds(
        (const __attribute__((address_space(1))) unsigned int*)g,
        (__attribute__((address_space(3))) unsigned int*)l,
        16, 0, 0);
}

__device__ __forceinline__ unsigned short f2bf_bits(float f) {
    bf16 h = __float2bfloat16(f);
    return *reinterpret_cast<unsigned short*>(&h);
}

__device__ __forceinline__ uint2 pack4bf(float a, float b, float c, float d) {
    __hip_bfloat162 lo = __float22bfloat162_rn(float2{a, b});
    __hip_bfloat162 hi = __float22bfloat162_rn(float2{c, d});
    uint2 r;
    r.x = *reinterpret_cast<unsigned*>(&lo);
    r.y = *reinterpret_cast<unsigned*>(&hi);
    return r;
}

// pack two f32 -> one dword of 2 bf16 (lo in [15:0], hi in [31:16]), RNE
__device__ __forceinline__ unsigned pkbf(float lo, float hi) {
    __hip_bfloat162 h = __float22bfloat162_rn(float2{lo, hi});
    return *reinterpret_cast<unsigned*>(&h);
}

// ---------------- prep: z=0..3 weight transpose+convert; z=4 x convert ----------------
__global__ __launch_bounds__(256) void prep_kernel(
        const float* __restrict__ x, const float* __restrict__ W0,
        const float* __restrict__ W1, const float* __restrict__ W2,
        const float* __restrict__ W3, bf16* __restrict__ xb,
        bf16* __restrict__ T0, bf16* __restrict__ T1,
        bf16* __restrict__ T2, bf16* __restrict__ T3) {
    const int tid = threadIdx.x + threadIdx.y * blockDim.x;  // 0..255
    if (blockIdx.z == 4) {
        // convert x: block (bx,by) -> chunk (by*32+bx) of 4096 floats
        int chunk = blockIdx.y * 32 + blockIdx.x;
        int base = chunk * 4096 + tid * 4;
        #pragma unroll
        for (int r = 0; r < 4; r++) {
            int i = base + r * 1024;
            float4 f = *reinterpret_cast<const float4*>(x + i);
            unsigned long long p = (unsigned long long)f2bf_bits(f.x)
                                 | ((unsigned long long)f2bf_bits(f.y) << 16)
                                 | ((unsigned long long)f2bf_bits(f.z) << 32)
                                 | ((unsigned long long)f2bf_bits(f.w) << 48);
            *reinterpret_cast<unsigned long long*>(xb + i) = p;
        }
        return;
    }
    const float* W; bf16* T;
    switch (blockIdx.z) {
        case 0:  W = W0; T = T0; break;
        case 1:  W = W1; T = T1; break;
        case 2:  W = W2; T = T2; break;
        default: W = W3; T = T3; break;
    }
    __shared__ float tile[32][33];
    int k0 = blockIdx.x * 32, n0 = blockIdx.y * 32;
    int tx = threadIdx.x, ty = threadIdx.y;
    #pragma unroll
    for (int i = 0; i < 4; i++)
        tile[ty + 8 * i][tx] = W[(size_t)(k0 + ty + 8 * i) * 1024 + n0 + tx];
    __syncthreads();
    #pragma unroll
    for (int i = 0; i < 4; i++)
        T[(size_t)(n0 + ty + 8 * i) * 1024 + k0 + tx] = __float2bfloat16(tile[tx][ty + 8 * i]);
}

// ---------------- 128x128 bf16 MFMA GEMM tile body (K=1024), m97-style ----------------
__device__ __forceinline__ void gemm128_body(const bf16* __restrict__ A,
                                             const bf16* __restrict__ Bt,
                                             int m0, int n0, floatx4 acc[4][4]) {
    __shared__ __align__(16) bf16 As[8192];
    __shared__ __align__(16) bf16 Bs[8192];
    const int tid = threadIdx.x;
    const int wave = tid >> 6;
    const int lane = tid & 63;
    const int l15 = lane & 15;
    const int quad = lane >> 4;

    #pragma unroll
    for (int i = 0; i < 4; i++)
        #pragma unroll
        for (int j = 0; j < 4; j++)
            acc[i][j] = (floatx4){0.f, 0.f, 0.f, 0.f};

    for (int k0 = 0; k0 < 1024; k0 += 64) {
        __syncthreads();
        #pragma unroll
        for (int j = 0; j < 4; j++) {
            int t = wave * 4 + j;
            int row = (t >> 1) * 16 + l15;
            int kb = (t & 1) * 32 + quad * 8;
            gll16(A + (size_t)(m0 + row) * 1024 + k0 + kb, &As[t * 512]);
            gll16(Bt + (size_t)(n0 + row) * 1024 + k0 + kb, &Bs[t * 512]);
        }
        __syncthreads();
        #pragma unroll
        for (int ks = 0; ks < 2; ks++) {
            short8 af[4], bfr[4];
            #pragma unroll
            for (int i = 0; i < 4; i++)
                af[i] = *reinterpret_cast<const short8*>(
                    &As[((((wave >> 1) * 4 + i) * 2 + ks) * 512) + lane * 8]);
            #pragma unroll
            for (int j = 0; j < 4; j++)
                bfr[j] = *reinterpret_cast<const short8*>(
                    &Bs[((((wave & 1) * 4 + j) * 2 + ks) * 512) + lane * 8]);
            #pragma unroll
            for (int i = 0; i < 4; i++)
                #pragma unroll
                for (int j = 0; j < 4; j++)
                    acc[i][j] = __builtin_amdgcn_mfma_f32_16x16x32_bf16(af[i], bfr[j], acc[i][j], 0, 0, 0);
        }
    }
}

// ---------------- QKV projection ----------------
// z=0: Q (scaled by beta*log2e so attention uses raw v_exp_f32; [h][seq][64])
// z=1: K ([h][seq][64])
// z=2: V written TRANSPOSED directly: Vt[h][d][seq] (b64 packed stores).
__global__ __launch_bounds__(256) void qkv_gemm_kernel(
        const bf16* __restrict__ xb,
        const bf16* __restrict__ Wqt, const bf16* __restrict__ Wkt, const bf16* __restrict__ Wvt,
        bf16* __restrict__ Qh, bf16* __restrict__ Kh, bf16* __restrict__ Vt) {
    const bf16* Bt;
    if (blockIdx.z == 0)      Bt = Wqt;
    else if (blockIdx.z == 1) Bt = Wkt;
    else                      Bt = Wvt;
    int n0 = blockIdx.x * 128, m0 = blockIdx.y * 128;
    floatx4 acc[4][4];
    gemm128_body(xb, Bt, m0, n0, acc);

    const int tid = threadIdx.x, wave = tid >> 6, lane = tid & 63;
    const int l15 = lane & 15, quad = lane >> 4;
    const int wm = (wave >> 1) * 64, wn = (wave & 1) * 64;
    if (blockIdx.z == 2) {
        #pragma unroll
        for (int i = 0; i < 4; i++)
            #pragma unroll
            for (int j = 0; j < 4; j++) {
                int col = n0 + wn + j * 16 + l15;
                int h = col >> 6, d = col & 63;
                int row0 = m0 + wm + i * 16 + quad * 4;
                uint2 v = pack4bf(acc[i][j][0], acc[i][j][1], acc[i][j][2], acc[i][j][3]);
                *reinterpret_cast<uint2*>(Vt + ((size_t)h * DHEAD + d) * SEQ + row0) = v;
            }
    } else {
        bf16* O = (blockIdx.z == 0) ? Qh : Kh;
        float scale = (blockIdx.z == 0) ? 0.125f * 1.4426950408889634f : 1.0f;
        #pragma unroll
        for (int i = 0; i < 4; i++)
            #pragma unroll
            for (int j = 0; j < 4; j++) {
                int col = n0 + wn + j * 16 + l15;
                int h = col >> 6, d = col & 63;
                #pragma unroll
                for (int r = 0; r < 4; r++) {
                    int row = m0 + wm + i * 16 + quad * 4 + r;
                    O[((size_t)h * SEQ + row) * DHEAD + d] = __float2bfloat16(acc[i][j][r] * scale);
                }
            }
    }
}

// ---------------- output projection: out = Oa @ Wo + bo (fp32 out) ----------------
__global__ __launch_bounds__(256) void out_gemm_kernel(
        const bf16* __restrict__ Oa, const bf16* __restrict__ Wot,
        const float* __restrict__ bo, float* __restrict__ out) {
    int n0 = blockIdx.x * 128, m0 = blockIdx.y * 128;
    floatx4 acc[4][4];
    gemm128_body(Oa, Wot, m0, n0, acc);

    const int tid = threadIdx.x, wave = tid >> 6, lane = tid & 63;
    const int l15 = lane & 15, quad = lane >> 4;
    const int wm = (wave >> 1) * 64, wn = (wave & 1) * 64;
    #pragma unroll
    for (int i = 0; i < 4; i++)
        #pragma unroll
        for (int j = 0; j < 4; j++) {
            int col = n0 + wn + j * 16 + l15;
            float b = bo[col];
            #pragma unroll
            for (int r = 0; r < 4; r++) {
                int row = m0 + wm + i * 16 + quad * 4 + r;
                out[(size_t)row * DIM + col] = acc[i][j][r] + b;
            }
        }
}

// ---------------- causal flash attention (R14: balanced trios over R13 core) ----------------
// POST-MORTEM R13: 32x32 MFMA + in-register P (T12) was time-neutral (77.5->76.5)
// but bank conflicts -> 0 and instructions/FLOP fell 3.6x; occupancy fell to 18%.
// Counter forensics: R13's piece map broke CU balance. Co-resident trio on a CU
// = ids {c, c+256, c+512} -> rk {r, r+16, r+32}; R13 lens were {32, 32-2r, 32-2r}
// -> trio sum 96-4r (CU0 96 units, CU15 36, mean 66). Wall = heaviest CU.
// R14 fix (ONE LINE): third class takes single t = rk-32 (len 2r+2):
// trio = {chunk0(16+r)=32, chunk1(31-r)=32-2r, single(r)=2r+2} = 66 for ALL r.
// Core unchanged from R13:
//   * mfma_f32_32x32x16_bf16; 4 waves x 32 q = 128-row blocks; BK=64 dbuf,
//     1 barrier/tile, LDS 32 KB; S^T=K.Q^T layout key=(reg&3)+8*(reg>>2)+4*half.
//   * P built IN-REGISTER (T12): 4 cvt_pk + 2 v_permlane32_swap_b32 per 16-key
//     slot; no Ps LDS; SQ_LDS_BANK_CONFLICT == 0 (verified R13).
//   * split-key additive partials (no max-subtraction softmax) + combine.
// p = v_exp_f32(s) via __builtin_amdgcn_exp2f — do NOT use exp2f (libcall,
// +15 µs R8). DO NOT: drop staging (R6), occupancy <4 blk/CU (R10),
// per-wave K/V-quarter split (R12), unbalanced piece maps (R13).
#define PV_STEP(P, KTG)                                                              \
    do {                                                                             \
        const int rb_ = ((KTG) & 1) * 8;                                             \
        unsigned A0_ = pkbf((P)[rb_ + 0], (P)[rb_ + 1]);                             \
        unsigned B0_ = pkbf((P)[rb_ + 4], (P)[rb_ + 5]);                             \
        unsigned A1_ = pkbf((P)[rb_ + 2], (P)[rb_ + 3]);                             \
        unsigned B1_ = pkbf((P)[rb_ + 6], (P)[rb_ + 7]);                             \
        asm("v_permlane32_swap_b32 %0, %1" : "+v"(A0_), "+v"(B0_));                  \
        asm("v_permlane32_swap_b32 %0, %1" : "+v"(A1_), "+v"(B1_));                  \
        uint4 w_; w_.x = A0_; w_.y = A1_; w_.z = B0_; w_.w = B1_;                    \
        short8 bp_ = *reinterpret_cast<short8*>(&w_);                                \
        short8 av0_ = *reinterpret_cast<const short8*>(                              \
            &Vsh[cur][(KTG) * 512 + lane * 8]);                                      \
        short8 av1_ = *reinterpret_cast<const short8*>(                              \
            &Vsh[cur][(4 + (KTG)) * 512 + lane * 8]);                                \
        acc0 = __builtin_amdgcn_mfma_f32_32x32x16_bf16(av0_, bp_, acc0, 0, 0, 0);    \
        acc1 = __builtin_amdgcn_mfma_f32_32x32x16_bf16(av1_, bp_, acc1, 0, 0, 0);    \
    } while (0)

__global__ __launch_bounds__(256, 4) void attention_kernel(
        const bf16* __restrict__ Qh, const bf16* __restrict__ Kh,
        const bf16* __restrict__ Vt, bf16* __restrict__ Oa,
        float* __restrict__ Op0, float* __restrict__ Op1,
        float* __restrict__ L0, float* __restrict__ L1) {
    __shared__ __align__(16) bf16 Ksh[2][4096];  // 8 KB/buf: chunk t=g*4+kc (keys g*32.., k kc*16..)
    __shared__ __align__(16) bf16 Vsh[2][4096];  // 8 KB/buf: chunk t=dg*4+kt (d dg*32.., key kt*16..)
    const int tid = threadIdx.x, wave = tid >> 6, lane = tid & 63;
    const int ql = lane & 31, half = lane >> 5;
    const int h8 = half * 8;
    const int id = blockIdx.x;
    const int head = id & 15;                    // XCD id&7 serves heads {h, h+8}
    const int rk = id >> 4;                      // 0..47
    // BALANCED piece map: co-resident trio rk {r, r+16, r+32} sums to 66:
    // rk<16:      chunk0 of t=16+rk          (len 32)
    // rk in 16..31: chunk1 of t=47-rk        (len 2t+2-32 = 32-2(rk-16))
    // rk in 32..47: single  t=rk-32          (len 2t+2 = 2(rk-32)+2)
    int t, ck;
    if (rk < 16)      { t = 16 + rk; ck = 0; }
    else if (rk < 32) { t = 47 - rk; ck = 1; }
    else              { t = rk - 32; ck = 0; }
    const bool split = (t >= 16);
    const int ktile0 = (split && ck == 1) ? 32 : 0;
    const int ktile1 = (split && ck == 0) ? 32 : (2 * t + 2);
    const int qw = t * 128 + wave * 32;          // wave's 32 q-rows
    const int q = qw + ql;                       // this lane's q-row (n = lane&31)
    const size_t hoff = (size_t)head * SEQ * DHEAD;
    const bf16* Qb = Qh + hoff;
    const bf16* Kb = Kh + hoff;
    const bf16* Vb = Vt + hoff;                  // [d][seq]

    // Q as B-frags for 32x32x16: lane n=q, k = kc*16 + 8*half + j
    short8 bq[4];
    #pragma unroll
    for (int kc = 0; kc < 4; kc++)
        bq[kc] = *reinterpret_cast<const short8*>(
            Qb + (size_t)q * DHEAD + kc * 16 + h8);

    floatx16 acc0, acc1;                         // O: d = (reg&3)+8*(reg>>2)+4*half (+32 for acc1), col q
    #pragma unroll
    for (int r = 0; r < 16; r++) { acc0[r] = 0.f; acc1[r] = 0.f; }
    float l_part = 0.f;

    // per-wave stage of one 64-key K tile + V tile into buffer `buf`
    auto stage = [&](int buf, int kbase) {
        #pragma unroll
        for (int j = 0; j < 2; j++) {
            int tc = wave * 2 + j;               // 0..7 across 4 waves
            gll16(Kb + (size_t)(kbase + (tc >> 2) * 32 + ql) * DHEAD + (tc & 3) * 16 + h8,
                  &Ksh[buf][tc * 512]);
            gll16(Vb + (size_t)((tc >> 2) * 32 + ql) * SEQ + kbase + (tc & 3) * 16 + h8,
                  &Vsh[buf][tc * 512]);
        }
    };

    stage(0, ktile0 * 64);
    __syncthreads();                             // vmcnt(0) drain + first tile visible
    int cur = 0;
    for (int kt = ktile0; kt < ktile1; kt++) {
        const int kbase = kt * 64;
        if (kt + 1 < ktile1) stage(cur ^ 1, (kt + 1) * 64);  // async prefetch

        // S^T = K·Q^T: 8 A-frag reads feed 8 32x32x16 MFMAs (2 key-groups)
        floatx16 s0, s1;
        #pragma unroll
        for (int r = 0; r < 16; r++) { s0[r] = 0.f; s1[r] = 0.f; }
        __builtin_amdgcn_s_setprio(1);
        #pragma unroll
        for (int kc = 0; kc < 4; kc++) {
            short8 ak0 = *reinterpret_cast<const short8*>(&Ksh[cur][kc * 512 + lane * 8]);
            short8 ak1 = *reinterpret_cast<const short8*>(&Ksh[cur][(4 + kc) * 512 + lane * 8]);
            s0 = __builtin_amdgcn_mfma_f32_32x32x16_bf16(ak0, bq[kc], s0, 0, 0, 0);
            s1 = __builtin_amdgcn_mfma_f32_32x32x16_bf16(ak1, bq[kc], s1, 0, 0, 0);
        }
        __builtin_amdgcn_s_setprio(0);
        // causal mask: key = kbase + 32*sg + (r&3)+8*(r>>2)+4*half, q = q
        if (kbase + 63 > qw) {                   // wave-uniform
            int base0 = kbase + half * 4 - q;
            #pragma unroll
            for (int r = 0; r < 16; r++) {
                int off = (r & 3) + 8 * (r >> 2);
                if (base0 + off > 0)      s0[r] = -1e30f;
                if (base0 + 32 + off > 0) s1[r] = -1e30f;
            }
        }
        // p = 2^s in place (masked -> 0); per-lane denom partial
        #pragma unroll
        for (int r = 0; r < 16; r++) {
            s0[r] = __builtin_amdgcn_exp2f(s0[r]);
            s1[r] = __builtin_amdgcn_exp2f(s1[r]);
            l_part += s0[r] + s1[r];
        }
        // O += V^T·P: per 16-key slot build bp in-register (T12) + 2 MFMAs
        __builtin_amdgcn_s_setprio(1);
        PV_STEP(s0, 0); PV_STEP(s0, 1); PV_STEP(s1, 2); PV_STEP(s1, 3);
        __builtin_amdgcn_s_setprio(0);

        __syncthreads();                         // readers done + prefetch drained
        cur ^= 1;
    }
    // denom: lane holds half the keys; other half sits at lane^32
    float l = l_part + __shfl_xor(l_part, 32, 64);
    if (!split) {
        // single-chunk: finalize. Oa row-major [SEQ][INNER].
        float rcp = 1.0f / l;
        #pragma unroll
        for (int a = 0; a < 4; a++) {
            int d0 = 8 * a + half * 4;
            uint2 v0 = pack4bf(acc0[4 * a + 0] * rcp, acc0[4 * a + 1] * rcp,
                               acc0[4 * a + 2] * rcp, acc0[4 * a + 3] * rcp);
            *reinterpret_cast<uint2*>(Oa + (size_t)q * INNER + head * DHEAD + d0) = v0;
            uint2 v1 = pack4bf(acc1[4 * a + 0] * rcp, acc1[4 * a + 1] * rcp,
                               acc1[4 * a + 2] * rcp, acc1[4 * a + 3] * rcp);
            *reinterpret_cast<uint2*>(Oa + (size_t)q * INNER + head * DHEAD + 32 + d0) = v1;
        }
    } else {
        // split: write unnormalized fp32 partials (q in [2048,4096))
        float* Op = ck ? Op1 : Op0;
        float* Lp = ck ? L1 : L0;
        if (half == 0) Lp[head * 2048 + (q - 2048)] = l;
        #pragma unroll
        for (int a = 0; a < 4; a++) {
            int d0 = 8 * a + half * 4;
            floatx4 v0 = {acc0[4 * a + 0], acc0[4 * a + 1], acc0[4 * a + 2], acc0[4 * a + 3]};
            *reinterpret_cast<floatx4*>(
                Op + (size_t)(q - 2048) * INNER + head * DHEAD + d0) = v0;
            floatx4 v1 = {acc1[4 * a + 0], acc1[4 * a + 1], acc1[4 * a + 2], acc1[4 * a + 3]};
            *reinterpret_cast<floatx4*>(
                Op + (size_t)(q - 2048) * INNER + head * DHEAD + 32 + d0) = v1;
        }
    }
}

// ---------------- combine: rows 2048..4095 = (O0+O1)/(l0+l1) -> bf16 Oa ----------------
__global__ __launch_bounds__(256) void combine_kernel(
        const float* __restrict__ Op0, const float* __restrict__ Op1,
        const float* __restrict__ L0, const float* __restrict__ L1,
        bf16* __restrict__ Oa) {
    int idx = blockIdx.x * 256 + threadIdx.x;    // 524288 threads, 4 floats each
    int row = idx >> 8;                          // 0..2047 (q = 2048 + row)
    int c4 = (idx & 255) * 4;                    // col base
    int head = c4 >> 6;
    float l = L0[head * 2048 + row] + L1[head * 2048 + row];
    float rcp = 1.0f / l;
    float4 a = *reinterpret_cast<const float4*>(Op0 + (size_t)row * INNER + c4);
    float4 b = *reinterpret_cast<const float4*>(Op1 + (size_t)row * INNER + c4);
    uint2 v = pack4bf((a.x + b.x) * rcp, (a.y + b.y) * rcp,
                      (a.z + b.z) * rcp, (a.w + b.w) * rcp);
    *reinterpret_cast<uint2*>(Oa + (size_t)(2048 + row) * INNER + c4) = v;
}

extern "C" void kernel_launch(void* const* d_in, const int* in_sizes, int n_in,
                              void* d_out, int out_size, void* d_ws, size_t ws_size,
                              hipStream_t stream) {
    const float* x  = (const float*)d_in[0];
    const float* Wq = (const float*)d_in[1];
    const float* Wk = (const float*)d_in[2];
    const float* Wv = (const float*)d_in[3];
    const float* Wo = (const float*)d_in[4];
    const float* bo = (const float*)d_in[5];
    float* out = (float*)d_out;

    char* ws = (char*)d_ws;
    size_t off = 0;
    bf16* xb  = (bf16*)(ws + off); off += (size_t)SEQ * DIM * 2;
    bf16* Wqt = (bf16*)(ws + off); off += (size_t)DIM * INNER * 2;
    bf16* Wkt = (bf16*)(ws + off); off += (size_t)DIM * INNER * 2;
    bf16* Wvt = (bf16*)(ws + off); off += (size_t)DIM * INNER * 2;
    bf16* Wot = (bf16*)(ws + off); off += (size_t)INNER * DIM * 2;
    bf16* Qh  = (bf16*)(ws + off); off += (size_t)NHEADS * SEQ * DHEAD * 2;
    bf16* Kh  = (bf16*)(ws + off); off += (size_t)NHEADS * SEQ * DHEAD * 2;
    bf16* Vtr = (bf16*)(ws + off); off += (size_t)NHEADS * DHEAD * SEQ * 2;
    bf16* Oa  = (bf16*)(ws + off); off += (size_t)SEQ * INNER * 2;
    float* Op0 = (float*)(ws + off); off += (size_t)(SEQ / 2) * INNER * 4;  // 8 MB
    float* Op1 = (float*)(ws + off); off += (size_t)(SEQ / 2) * INNER * 4;  // 8 MB
    float* L0  = (float*)(ws + off); off += (size_t)NHEADS * (SEQ / 2) * 4;
    float* L1  = (float*)(ws + off); off += (size_t)NHEADS * (SEQ / 2) * 4;  // ~64.5 MB total

    prep_kernel<<<dim3(32, 32, 5), dim3(32, 8), 0, stream>>>(x, Wq, Wk, Wv, Wo,
                                                             xb, Wqt, Wkt, Wvt, Wot);
    qkv_gemm_kernel<<<dim3(8, 32, 3), 256, 0, stream>>>(xb, Wqt, Wkt, Wvt, Qh, Kh, Vtr);
    attention_kernel<<<768, 256, 0, stream>>>(Qh, Kh, Vtr, Oa, Op0, Op1, L0, L1);
    combine_kernel<<<2048, 256, 0, stream>>>(Op0, Op1, L0, L1, Oa);
    out_gemm_kernel<<<dim3(8, 32), 256, 0, stream>>>(Oa, Wot, bo, out);
}